// Round 5
// baseline (114.106 us; speedup 1.0000x reference)
//
#include <hip/hip_runtime.h>
#include <stdint.h>
#include <stddef.h>

// Problem: out[b,a,o] = sum_{i,j} h0[b,a,i] h1[b,a,j] T[a,i,j,o], h=concat(x,1)
// GEMM form: C[b,o] += G[b,k]*Tb[a,k,o]; main k=j*128+i (i,j<128); k=16384+c:
// G=h1[c]; k=16512+c: G=h0[c]; k=16640: G=1. 261 K-tiles of 64.
#define NA     4
#define DDIM   128
#define OUTD   128
#define BM     256
#define BN     128
#define NTILES 261
#define TILE_B 16384          // BN * 64 * 2B
#define OUT_ELEMS (4096 * NA * OUTD)   // 2,097,152 f32

typedef _Float16 f16;
typedef __attribute__((ext_vector_type(8)))  _Float16 f16x8;
typedef __attribute__((ext_vector_type(4)))  float    f32x4;
typedef __attribute__((ext_vector_type(16))) float    f32x16;

static const size_t TB_BYTES  = (size_t)NA * NTILES * TILE_B;          // 17,104,896
static const size_t P_BYTES   = (size_t)4 * OUT_ELEMS * sizeof(float); // 33,554,432
static const size_t WS_NEEDED = TB_BYTES + P_BYTES;                    // ~50.7 MB

typedef const __attribute__((address_space(1))) unsigned int guint_t;
typedef __attribute__((address_space(3))) unsigned int luint_t;

__device__ __forceinline__ void async_copy16(const void* g, void* l) {
    __builtin_amdgcn_global_load_lds((guint_t*)g, (luint_t*)l, 16, 0, 0);
}

// ---------------------------------------------------------------------------
// Prep: T f32 -> Tb f16, per (a,tile) a 16KB image; unit v = w*128+col
// (w=0..7) holds k = tile*64 + w*8 + e at output-col `col`.
// ---------------------------------------------------------------------------
__global__ __launch_bounds__(256) void prep_kernel(const float* __restrict__ T,
                                                   f16* __restrict__ Tb) {
    int blk  = blockIdx.x;            // a*NTILES + tile
    int a    = blk / NTILES;
    int tile = blk - a * NTILES;
    int t    = threadIdx.x;
    f16* base = Tb + (size_t)blk * (TILE_B / 2);
    #pragma unroll
    for (int u = 0; u < 4; ++u) {
        int v   = t + u * 256;
        int w   = v >> 7;
        int col = v & 127;
        f16x8 ov;
        #pragma unroll
        for (int e = 0; e < 8; ++e) {
            int k = tile * 64 + w * 8 + e;
            int i = -1, j = 0;
            if (k < 16384)       { i = k & 127;   j = k >> 7;    }
            else if (k < 16512)  { i = 128;       j = k - 16384; }
            else if (k < 16640)  { i = k - 16512; j = 128;       }
            else if (k == 16640) { i = 128;       j = 128;       }
            float val = 0.f;
            if (i >= 0) val = T[(((size_t)a * 129 + i) * 129 + j) * 128 + col];
            ov[e] = (f16)val;
        }
        *(f16x8*)(base + (size_t)v * 8) = ov;
    }
}

// ---------------------------------------------------------------------------
// GEMM: BM=256 x BN=128, BK=64, 8 waves as 2M x 4N (wave = 128 rows x 32
// cols) -> B-LDS-read redundancy 2x instead of 4x (the round-4 wall).
// A built in registers (h0reg[4][8], h1 scalar). Raw barrier + counted
// vmcnt(2). Tail correction tiles per-ks: ks0->256, ks1->{258,260},
// ks2->257, ks3->259. h1t window: jbase=ks*32, 64 j's for ks 0/2.
// ---------------------------------------------------------------------------
template <bool ATOMIC>
__global__ __launch_bounds__(512, 2) void gemm_kernel(const float* __restrict__ x0,
                                                      const float* __restrict__ x1,
                                                      const f16* __restrict__ Tb,
                                                      float* __restrict__ dst) {
    __shared__ __align__(16) f16  h1t[64 * 256];    // 32KB window of h1 (transposed)
    __shared__ __align__(16) char Bs[3][TILE_B];    // 48KB triple buffer

    int bid  = blockIdx.x;
    int xcd  = bid & 7, idx = bid >> 3;
    int pair = xcd * 2 + (idx >> 4);  // (a,ks) pairs contiguous per XCD
    int mt   = idx & 15;
    int a    = pair & 3;
    int ks   = pair >> 2;

    int t    = threadIdx.x;
    int lane = t & 63, wid = t >> 6;
    int wm   = wid >> 2, wn = wid & 3;       // 2M x 4N
    int l31  = lane & 31, hi = lane >> 5;
    int b0   = mt * BM;

    const char* tbb = (const char*)Tb + (size_t)a * NTILES * TILE_B;
    int nt    = (ks == 1) ? 66 : 65;
    int jbase = ks * 32;
    int jn    = (ks == 0 || ks == 2) ? 64 : 32;

    auto tile_at = [&](int tt) -> int {
        if (tt < 64) return ks * 64 + tt;
        if (ks == 0) return 256;
        if (ks == 1) return (tt == 64) ? 258 : 260;
        if (ks == 2) return 257;
        return 259;
    };
    auto stage = [&](int tt, int buf) {
        const char* src = tbb + (size_t)tile_at(tt) * TILE_B + wid * 2048 + lane * 16;
        char* dstl = &Bs[buf][wid * 2048];
        async_copy16(src,        dstl);
        async_copy16(src + 1024, dstl + 1024);
    };

    stage(0, 0);
    stage(1, 1);

    // ---- one-time h1 window -> LDS (transposed, f16) ----
    {
        int row = t & 255, hs = t >> 8;
        const float* x1r = x1 + ((size_t)(b0 + row) * NA + a) * DDIM + jbase;
        int half = jn >> 1;                       // 16 or 32
        for (int q = hs * (half >> 2); q < (hs + 1) * (half >> 2); ++q) {
            f32x4 v = *(const f32x4*)(x1r + q * 4);
            #pragma unroll
            for (int e = 0; e < 4; ++e)
                h1t[(q * 4 + e) * 256 + row] = (f16)v[e];
        }
    }
    // ---- one-time h0 -> registers (4 rows/lane, window-halved by hi) ----
    f16x8 h0reg[4][8];
    #pragma unroll
    for (int fm = 0; fm < 4; ++fm) {
        int row = b0 + wm * 128 + fm * 32 + l31;
        const float* x0r = x0 + ((size_t)row * NA + a) * DDIM;
        #pragma unroll
        for (int w = 0; w < 8; ++w) {
            int wf = 2 * w + hi;
            f32x4 v0 = *(const f32x4*)(x0r + wf * 8);
            f32x4 v1 = *(const f32x4*)(x0r + wf * 8 + 4);
            f16x8 h;
            #pragma unroll
            for (int e = 0; e < 4; ++e) { h[e] = (f16)v0[e]; h[e + 4] = (f16)v1[e]; }
            h0reg[fm][w] = h;
        }
    }
    __syncthreads();   // full drain once: h1t visible; Bs[0..1] also landed

    f32x16 acc[4];
    #pragma unroll
    for (int i = 0; i < 4; ++i) acc[i] = (f32x16)0.f;

    // ---- main loop: 64 tiles; raw barrier, counted vmcnt(2) ----
    for (int p = 0; p < 32; ++p) {
        f16 h1v[4];
        #pragma unroll
        for (int fm = 0; fm < 4; ++fm)
            h1v[fm] = h1t[p * 256 + (wm * 128 + fm * 32 + l31)];
        #pragma unroll
        for (int par = 0; par < 2; ++par) {
            int tt = 2 * p + par;
            asm volatile("s_waitcnt vmcnt(2)" ::: "memory");  // tile tt landed (self)
            __builtin_amdgcn_s_barrier();                     // landed for everyone
            asm volatile("" ::: "memory");
            if (tt + 2 < nt) stage(tt + 2, (tt + 2) % 3);
            const char* bb = Bs[tt % 3];
            __builtin_amdgcn_s_setprio(1);
            #pragma unroll
            for (int kk = 0; kk < 4; ++kk) {
                f16x8 bf = *(const f16x8*)(bb + ((kk * 2 + hi) * 128 + wn * 32 + l31) * 16);
                #pragma unroll
                for (int fm = 0; fm < 4; ++fm) {
                    f16x8 af = h0reg[fm][par * 4 + kk] * h1v[fm];
                    acc[fm] = __builtin_amdgcn_mfma_f32_32x32x16_f16(af, bf, acc[fm], 0, 0, 0);
                }
            }
            __builtin_amdgcn_s_setprio(0);
        }
    }

    // ---- correction tail (1-2 tiles, per-ks role) ----
    for (int tt = 64; tt < nt; ++tt) {
        if (tt + 1 < nt) asm volatile("s_waitcnt vmcnt(2)" ::: "memory");
        else             asm volatile("s_waitcnt vmcnt(0)" ::: "memory");
        __builtin_amdgcn_s_barrier();
        asm volatile("" ::: "memory");
        const char* bb = Bs[tt % 3];
        bool icorr_lo = (ks == 1) && (tt == 64);
        bool onehot   = (ks == 1) && (tt == 65);

        __builtin_amdgcn_s_setprio(1);
        #pragma unroll
        for (int kk = 0; kk < 4; ++kk) {
            f16x8 bf = *(const f16x8*)(bb + ((kk * 2 + hi) * 128 + wn * 32 + l31) * 16);
            #pragma unroll
            for (int fm = 0; fm < 4; ++fm) {
                f16x8 af;
                if (ks == 0 || ks == 2) {            // j-corr: G = h1[c]
                    int row = wm * 128 + fm * 32 + l31;
                    #pragma unroll
                    for (int e = 0; e < 8; ++e)
                        af[e] = h1t[(kk * 16 + hi * 8 + e) * 256 + row];
                } else if (ks == 3) {                // i-corr hi: G = h0[64+c]
                    af = h0reg[fm][4 + kk];
                } else if (icorr_lo) {               // i-corr lo: G = h0[c]
                    af = h0reg[fm][kk];
                } else {                             // const: G = 1 at k_local 0
                    af = (f16x8)(f16)0.f;
                    if (kk == 0 && hi == 0) af[0] = (f16)1.f;
                }
                (void)onehot;
                acc[fm] = __builtin_amdgcn_mfma_f32_32x32x16_f16(af, bf, acc[fm], 0, 0, 0);
            }
        }
        __builtin_amdgcn_s_setprio(0);
    }

    // ---- epilogue: C/D 32x32 layout col=lane&31, row=(r&3)+8*(r>>2)+4*hi ----
    float* base = ATOMIC ? dst : dst + (size_t)ks * OUT_ELEMS;
    #pragma unroll
    for (int fm = 0; fm < 4; ++fm)
        #pragma unroll
        for (int r = 0; r < 16; ++r) {
            int row = b0 + wm * 128 + fm * 32 + (r & 3) + 8 * (r >> 2) + 4 * hi;
            int col = wn * 32 + l31;
            size_t off = ((size_t)row * NA + a) * OUTD + col;
            if (ATOMIC) unsafeAtomicAdd(&base[off], acc[fm][r]);
            else        base[off] = acc[fm][r];
        }
}

// ---------------------------------------------------------------------------
// Reduce: out = P0 + P1 + P2 + P3 (f32x4 vectorized)
// ---------------------------------------------------------------------------
__global__ __launch_bounds__(256) void reduce_kernel(const float* __restrict__ P,
                                                     float* __restrict__ out) {
    int i = blockIdx.x * 256 + threadIdx.x;     // 524288 vec4 elems
    f32x4 s = ((const f32x4*)P)[i];
    s += ((const f32x4*)(P + OUT_ELEMS))[i];
    s += ((const f32x4*)(P + 2 * (size_t)OUT_ELEMS))[i];
    s += ((const f32x4*)(P + 3 * (size_t)OUT_ELEMS))[i];
    ((f32x4*)out)[i] = s;
}

// ---------------------------------------------------------------------------
// Fallback (ws too small): naive but correct f32 kernel.
// ---------------------------------------------------------------------------
__global__ __launch_bounds__(128) void fallback_kernel(const float* __restrict__ x0,
                                                       const float* __restrict__ x1,
                                                       const float* __restrict__ T,
                                                       float* __restrict__ out) {
    int ba = blockIdx.x;
    int b = ba >> 2, a = ba & 3;
    int o = threadIdx.x;
    const float* h0 = x0 + ((size_t)b * NA + a) * DDIM;
    const float* h1 = x1 + ((size_t)b * NA + a) * DDIM;
    float acc = 0.f;
    for (int i = 0; i < 129; ++i) {
        float h0i = (i < 128) ? h0[i] : 1.f;
        const float* Trow = T + (((size_t)a * 129 + i) * 129) * 128 + o;
        float part = 0.f;
        for (int j = 0; j < 129; ++j) {
            float h1j = (j < 128) ? h1[j] : 1.f;
            part += h1j * Trow[(size_t)j * 128];
        }
        acc += h0i * part;
    }
    out[((size_t)b * NA + a) * OUTD + o] = acc;
}

extern "C" void kernel_launch(void* const* d_in, const int* in_sizes, int n_in,
                              void* d_out, int out_size, void* d_ws, size_t ws_size,
                              hipStream_t stream) {
    const float* x0 = (const float*)d_in[0];
    const float* x1 = (const float*)d_in[1];
    const float* T  = (const float*)d_in[2];
    float* out = (float*)d_out;

    if (ws_size < TB_BYTES) {
        fallback_kernel<<<4096 * NA, 128, 0, stream>>>(x0, x1, T, out);
        return;
    }

    f16* Tb = (f16*)d_ws;
    prep_kernel<<<NA * NTILES, 256, 0, stream>>>(T, Tb);

    if (ws_size >= WS_NEEDED) {
        float* P = (float*)((char*)d_ws + TB_BYTES);
        gemm_kernel<false><<<256, 512, 0, stream>>>(x0, x1, Tb, P);
        reduce_kernel<<<OUT_ELEMS / 4 / 256, 256, 0, stream>>>(P, out);
    } else {
        hipMemsetAsync(d_out, 0, (size_t)out_size * sizeof(float), stream);
        gemm_kernel<true><<<256, 512, 0, stream>>>(x0, x1, Tb, out);
    }
}